// Round 1
// baseline (353.137 us; speedup 1.0000x reference)
//
#include <hip/hip_runtime.h>
#include <hip/hip_bf16.h>

typedef __bf16 bf16_t;
typedef __bf16 bf16x8 __attribute__((ext_vector_type(8)));
typedef float f32x4 __attribute__((ext_vector_type(4)));

#define MFMA16(a, b, c) __builtin_amdgcn_mfma_f32_16x16x32_bf16((a), (b), (c), 0, 0, 0)

// B=4, T=2048, D=512, H=8, DH=64 — hardcoded
// ---------------------------------------------------------------------------
// fp32 -> bf16 elementwise convert (4 elems/thread)
__global__ __launch_bounds__(256) void k_cvt_bf16(const float* __restrict__ in,
                                                  bf16_t* __restrict__ out, int n4) {
  int i = blockIdx.x * 256 + threadIdx.x;
  if (i >= n4) return;
  float4 f = ((const float4*)in)[i];
  union { bf16_t h[4]; uint2 u; } cv;
  cv.h[0] = (bf16_t)f.x; cv.h[1] = (bf16_t)f.y; cv.h[2] = (bf16_t)f.z; cv.h[3] = (bf16_t)f.w;
  ((uint2*)out)[i] = cv.u;
}

// transpose W[K][N] -> WT[N][K], fp32 -> bf16 (coalesced both sides via LDS tile)
__global__ __launch_bounds__(256) void k_transpose_bf16(const float* __restrict__ W,
                                                        bf16_t* __restrict__ WT,
                                                        int K, int N) {
  __shared__ float tile[64][65];
  int bk = blockIdx.x * 64, bn = blockIdx.y * 64;
  int tx = threadIdx.x & 63, ty = threadIdx.x >> 6;
  for (int i = ty; i < 64; i += 4)
    tile[i][tx] = W[(size_t)(bk + i) * N + bn + tx];
  __syncthreads();
  for (int i = ty; i < 64; i += 4)
    WT[(size_t)(bn + i) * K + bk + tx] = (bf16_t)tile[tx][i];
}

// ---------------------------------------------------------------------------
// C[M][N] = A[M][K] @ Bt[N][K]^T, bf16 in, fp32 accum. 128x128 tile, 4 waves,
// BK=32, each wave 64x64 via 4x4 fragments of 16x16x32 MFMA.
// MODE 0: fp32 C   1: bf16 C   2: q/k scatter [B,H,T,DH]
// MODE 3: v scatter transposed [B,H,DH,T]     4: GELU poly -> bf16 C
template <int MODE>
__global__ __launch_bounds__(256) void k_gemm_bt(
    const bf16_t* __restrict__ A, const bf16_t* __restrict__ Bt,
    float* __restrict__ Cf, bf16_t* __restrict__ Cb,
    int M, int N, int K, const float* __restrict__ coef) {
  __shared__ __align__(16) bf16_t As[128 * 32];
  __shared__ __align__(16) bf16_t Bs[128 * 32];
  int tid = threadIdx.x;
  int lane = tid & 63, wave = tid >> 6;
  int bm = blockIdx.x * 128, bn = blockIdx.y * 128;
  int wr = (wave >> 1) * 64, wc = (wave & 1) * 64;
  int lr = lane & 15, lk = (lane >> 4) * 8;
  int srow = tid >> 2, scol = (tid & 3) * 8;

  f32x4 zero = {0.f, 0.f, 0.f, 0.f};
  f32x4 acc[4][4];
#pragma unroll
  for (int m = 0; m < 4; ++m)
#pragma unroll
    for (int n = 0; n < 4; ++n) acc[m][n] = zero;

  const size_t sA = (size_t)(bm + srow) * K + scol;
  const size_t sB = (size_t)(bn + srow) * K + scol;
  for (int k0 = 0; k0 < K; k0 += 32) {
    __syncthreads();
    *(uint4*)&As[srow * 32 + scol]        = *(const uint4*)&A[sA + k0];
    *(uint4*)&As[(srow + 64) * 32 + scol] = *(const uint4*)&A[sA + (size_t)64 * K + k0];
    *(uint4*)&Bs[srow * 32 + scol]        = *(const uint4*)&Bt[sB + k0];
    *(uint4*)&Bs[(srow + 64) * 32 + scol] = *(const uint4*)&Bt[sB + (size_t)64 * K + k0];
    __syncthreads();
    bf16x8 a[4], b[4];
#pragma unroll
    for (int m = 0; m < 4; ++m) a[m] = *(const bf16x8*)&As[(wr + m * 16 + lr) * 32 + lk];
#pragma unroll
    for (int n = 0; n < 4; ++n) b[n] = *(const bf16x8*)&Bs[(wc + n * 16 + lr) * 32 + lk];
#pragma unroll
    for (int m = 0; m < 4; ++m)
#pragma unroll
      for (int n = 0; n < 4; ++n)
        acc[m][n] = MFMA16(a[m], b[n], acc[m][n]);
  }

  float c8[8];
  if (MODE == 4) {
#pragma unroll
    for (int i = 0; i < 8; ++i) c8[i] = coef[i];
  }
  int rbase = (lane >> 4) * 4;
#pragma unroll
  for (int m = 0; m < 4; ++m) {
#pragma unroll
    for (int n = 0; n < 4; ++n) {
#pragma unroll
      for (int r = 0; r < 4; ++r) {
        int gm = bm + wr + m * 16 + rbase + r;
        int gn = bn + wc + n * 16 + lr;
        float v = acc[m][n][r];
        if (MODE == 0) {
          Cf[(size_t)gm * N + gn] = v;
        } else if (MODE == 1) {
          Cb[(size_t)gm * N + gn] = (bf16_t)v;
        } else if (MODE == 2) {
          int b_ = gm >> 11, t_ = gm & 2047, h_ = gn >> 6, d_ = gn & 63;
          Cb[(((size_t)b_ * 8 + h_) * 2048 + t_) * 64 + d_] = (bf16_t)v;
        } else if (MODE == 3) {
          int b_ = gm >> 11, t_ = gm & 2047, h_ = gn >> 6, d_ = gn & 63;
          Cb[(((size_t)b_ * 8 + h_) * 64 + d_) * 2048 + t_] = (bf16_t)v;
        } else {  // 4: GELU degree-7 poly on clipped input, iterative-power form
          float xx = fminf(fmaxf(v, -4.f), 4.f);
          float p = c8[0], pw = 1.f;
#pragma unroll
          for (int i = 1; i < 8; ++i) { pw *= xx; p += c8[i] * pw; }
          Cb[(size_t)gm * N + gn] = (bf16_t)p;
        }
      }
    }
  }
}

// ---------------------------------------------------------------------------
// Two-pass attention: per block one 64-row Q tile of one (b,h). 4 waves x 16 rows.
// Pass 1: row max of scores over all T. Pass 2: e=max(poly((s-max)/8),1e-8),
// accumulate rowsum and O += E @ V; O /= rowsum. exp poly must match reference.
__global__ __launch_bounds__(256) void k_attn(
    const bf16_t* __restrict__ qb, const bf16_t* __restrict__ kb,
    const bf16_t* __restrict__ vtb, bf16_t* __restrict__ ob,
    const float* __restrict__ exp_c) {
  __shared__ __align__(16) bf16_t Qs[64 * 64];
  __shared__ __align__(16) bf16_t Ks[64 * 64];
  __shared__ __align__(16) bf16_t Vs[64 * 64];
  __shared__ __align__(16) bf16_t Es[64 * 64];
  int tid = threadIdx.x, lane = tid & 63, wave = tid >> 6;
  int bid = blockIdx.x;
  int qt = bid & 31, bh = bid >> 5;
  const size_t bho = (size_t)bh * (2048 * 64);
  const bf16_t* Q = qb + bho + (size_t)qt * 64 * 64;
  const bf16_t* Kp = kb + bho;
  const bf16_t* Vp = vtb + bho;  // [64 dh][2048 t]

  int srow = tid >> 3, scol = (tid & 7) * 8;
  *(uint4*)&Qs[srow * 64 + scol]        = *(const uint4*)&Q[srow * 64 + scol];
  *(uint4*)&Qs[(srow + 32) * 64 + scol] = *(const uint4*)&Q[(srow + 32) * 64 + scol];

  float ec[7];
#pragma unroll
  for (int i = 0; i < 7; ++i) ec[i] = exp_c[i];

  int lr = lane & 15, lg = lane >> 4, lk = lg * 8;
  __syncthreads();
  bf16x8 qa0 = *(const bf16x8*)&Qs[(wave * 16 + lr) * 64 + lk];
  bf16x8 qa1 = *(const bf16x8*)&Qs[(wave * 16 + lr) * 64 + 32 + lk];

  f32x4 zero = {0.f, 0.f, 0.f, 0.f};
  // ---- pass 1: row max (on raw s; scale by 1/8 is positive-monotone)
  float rmax[4] = {-3.4e38f, -3.4e38f, -3.4e38f, -3.4e38f};
  for (int kt = 0; kt < 32; ++kt) {
    __syncthreads();
    *(uint4*)&Ks[srow * 64 + scol]        = *(const uint4*)&Kp[((size_t)kt * 64 + srow) * 64 + scol];
    *(uint4*)&Ks[(srow + 32) * 64 + scol] = *(const uint4*)&Kp[((size_t)kt * 64 + srow + 32) * 64 + scol];
    __syncthreads();
#pragma unroll
    for (int n = 0; n < 4; ++n) {
      f32x4 s = zero;
      bf16x8 b0 = *(const bf16x8*)&Ks[(n * 16 + lr) * 64 + lk];
      bf16x8 b1 = *(const bf16x8*)&Ks[(n * 16 + lr) * 64 + 32 + lk];
      s = MFMA16(qa0, b0, s);
      s = MFMA16(qa1, b1, s);
#pragma unroll
      for (int r = 0; r < 4; ++r) rmax[r] = fmaxf(rmax[r], s[r]);
    }
  }
#pragma unroll
  for (int off = 1; off < 16; off <<= 1)
#pragma unroll
    for (int r = 0; r < 4; ++r) rmax[r] = fmaxf(rmax[r], __shfl_xor(rmax[r], off));

  // ---- pass 2
  f32x4 oacc[4];
#pragma unroll
  for (int n = 0; n < 4; ++n) oacc[n] = zero;
  float rsum[4] = {0.f, 0.f, 0.f, 0.f};
  for (int kt = 0; kt < 32; ++kt) {
    __syncthreads();
    *(uint4*)&Ks[srow * 64 + scol]        = *(const uint4*)&Kp[((size_t)kt * 64 + srow) * 64 + scol];
    *(uint4*)&Ks[(srow + 32) * 64 + scol] = *(const uint4*)&Kp[((size_t)kt * 64 + srow + 32) * 64 + scol];
    *(uint4*)&Vs[srow * 64 + scol]        = *(const uint4*)&Vp[(size_t)srow * 2048 + kt * 64 + scol];
    *(uint4*)&Vs[(srow + 32) * 64 + scol] = *(const uint4*)&Vp[(size_t)(srow + 32) * 2048 + kt * 64 + scol];
    __syncthreads();
#pragma unroll
    for (int n = 0; n < 4; ++n) {
      f32x4 s = zero;
      bf16x8 b0 = *(const bf16x8*)&Ks[(n * 16 + lr) * 64 + lk];
      bf16x8 b1 = *(const bf16x8*)&Ks[(n * 16 + lr) * 64 + 32 + lk];
      s = MFMA16(qa0, b0, s);
      s = MFMA16(qa1, b1, s);
#pragma unroll
      for (int r = 0; r < 4; ++r) {
        float x = (s[r] - rmax[r]) * 0.125f;  // == s/8 - max/8 exactly (pow2)
        float p = ec[0], pw = 1.f;
#pragma unroll
        for (int i = 1; i < 7; ++i) { pw *= x; p += ec[i] * pw; }
        p = fmaxf(p, 1e-8f);
        rsum[r] += p;
        Es[(wave * 16 + lg * 4 + r) * 64 + n * 16 + lr] = (bf16_t)p;
      }
    }
    __syncthreads();
    bf16x8 ea0 = *(const bf16x8*)&Es[(wave * 16 + lr) * 64 + lk];
    bf16x8 ea1 = *(const bf16x8*)&Es[(wave * 16 + lr) * 64 + 32 + lk];
#pragma unroll
    for (int n = 0; n < 4; ++n) {
      bf16x8 v0 = *(const bf16x8*)&Vs[(n * 16 + lr) * 64 + lk];
      bf16x8 v1 = *(const bf16x8*)&Vs[(n * 16 + lr) * 64 + 32 + lk];
      oacc[n] = MFMA16(ea0, v0, oacc[n]);
      oacc[n] = MFMA16(ea1, v1, oacc[n]);
    }
  }
#pragma unroll
  for (int off = 1; off < 16; off <<= 1)
#pragma unroll
    for (int r = 0; r < 4; ++r) rsum[r] += __shfl_xor(rsum[r], off);

  int b_ = bh >> 3, h_ = bh & 7;
#pragma unroll
  for (int n = 0; n < 4; ++n)
#pragma unroll
    for (int r = 0; r < 4; ++r) {
      int t_ = qt * 64 + wave * 16 + lg * 4 + r;
      int d_ = n * 16 + lr;
      float val = oacc[n][r] / rsum[r];
      ob[(((size_t)b_ * 2048 + t_) * 8 + h_) * 64 + d_] = (bf16_t)val;
    }
}

// ---------------------------------------------------------------------------
// Fused residual + LayerNorm (replicates Newton rsqrt exactly: 3 iters from 0.5).
// One wave per row of 512; writes fp32 and optionally bf16.
__global__ __launch_bounds__(256) void k_ln(
    const float* __restrict__ xa, const float* __restrict__ xb,
    const float* __restrict__ gamma, const float* __restrict__ beta,
    float* __restrict__ outf, bf16_t* __restrict__ outb) {
  int row = blockIdx.x * 4 + (threadIdx.x >> 6);
  int lane = threadIdx.x & 63;
  const float* pa = xa + (size_t)row * 512;
  const float* pb = xb + (size_t)row * 512;
  float4 a0 = ((const float4*)pa)[lane];
  float4 a1 = ((const float4*)pa)[lane + 64];
  float4 b0 = ((const float4*)pb)[lane];
  float4 b1 = ((const float4*)pb)[lane + 64];
  float x[8] = {a0.x + b0.x, a0.y + b0.y, a0.z + b0.z, a0.w + b0.w,
                a1.x + b1.x, a1.y + b1.y, a1.z + b1.z, a1.w + b1.w};
  float s = 0.f, sq = 0.f;
#pragma unroll
  for (int i = 0; i < 8; ++i) { s += x[i]; sq += x[i] * x[i]; }
#pragma unroll
  for (int off = 1; off < 64; off <<= 1) {
    s += __shfl_xor(s, off);
    sq += __shfl_xor(sq, off);
  }
  float mean = s * (1.f / 512.f);
  float var = sq * (1.f / 512.f) - mean * mean;
  float v = var + 1e-5f;
  float y = 0.5f;
#pragma unroll
  for (int it = 0; it < 3; ++it) y = y * (3.0f - v * y * y) * 0.5f;

  float4 g0 = ((const float4*)gamma)[lane];
  float4 g1 = ((const float4*)gamma)[lane + 64];
  float4 e0 = ((const float4*)beta)[lane];
  float4 e1 = ((const float4*)beta)[lane + 64];
  float o[8];
  o[0] = (x[0] - mean) * y * g0.x + e0.x;
  o[1] = (x[1] - mean) * y * g0.y + e0.y;
  o[2] = (x[2] - mean) * y * g0.z + e0.z;
  o[3] = (x[3] - mean) * y * g0.w + e0.w;
  o[4] = (x[4] - mean) * y * g1.x + e1.x;
  o[5] = (x[5] - mean) * y * g1.y + e1.y;
  o[6] = (x[6] - mean) * y * g1.z + e1.z;
  o[7] = (x[7] - mean) * y * g1.w + e1.w;
  float* po = outf + (size_t)row * 512;
  ((float4*)po)[lane]      = make_float4(o[0], o[1], o[2], o[3]);
  ((float4*)po)[lane + 64] = make_float4(o[4], o[5], o[6], o[7]);
  if (outb) {
    bf16_t* pq = outb + (size_t)row * 512;
    union { bf16_t h[4]; uint2 u; } c0, c1;
    c0.h[0] = (bf16_t)o[0]; c0.h[1] = (bf16_t)o[1]; c0.h[2] = (bf16_t)o[2]; c0.h[3] = (bf16_t)o[3];
    c1.h[0] = (bf16_t)o[4]; c1.h[1] = (bf16_t)o[5]; c1.h[2] = (bf16_t)o[6]; c1.h[3] = (bf16_t)o[7];
    ((uint2*)pq)[lane]      = c0.u;
    ((uint2*)pq)[lane + 64] = c1.u;
  }
}

// ---------------------------------------------------------------------------
extern "C" void kernel_launch(void* const* d_in, const int* in_sizes, int n_in,
                              void* d_out, int out_size, void* d_ws, size_t ws_size,
                              hipStream_t stream) {
  const float* x      = (const float*)d_in[0];
  const float* Wq     = (const float*)d_in[1];
  const float* Wk     = (const float*)d_in[2];
  const float* Wv     = (const float*)d_in[3];
  const float* Wo     = (const float*)d_in[4];
  const float* W1     = (const float*)d_in[5];
  const float* W2     = (const float*)d_in[6];
  const float* g1     = (const float*)d_in[7];
  const float* b1     = (const float*)d_in[8];
  const float* g2     = (const float*)d_in[9];
  const float* b2     = (const float*)d_in[10];
  const float* gelu_c = (const float*)d_in[11];
  const float* exp_c  = (const float*)d_in[12];

  const int M = 8192;            // B*T
  const size_t actBF = (size_t)M * 512 * 2;   // 8 MB bf16 activation
  char* p = (char*)d_ws;
  auto carve = [&](size_t bytes) {
    void* r = (void*)p;
    p += (bytes + 255) & ~(size_t)255;
    return r;
  };
  bf16_t* x_bf  = (bf16_t*)carve(actBF);
  bf16_t* q_bf  = (bf16_t*)carve(actBF);
  bf16_t* k_bf  = (bf16_t*)carve(actBF);
  bf16_t* vT_bf = (bf16_t*)carve(actBF);
  bf16_t* o_bf  = (bf16_t*)carve(actBF);
  bf16_t* h_bf  = (bf16_t*)carve(actBF);
  bf16_t* WqT   = (bf16_t*)carve(512 * 512 * 2);
  bf16_t* WkT   = (bf16_t*)carve(512 * 512 * 2);
  bf16_t* WvT   = (bf16_t*)carve(512 * 512 * 2);
  bf16_t* WoT   = (bf16_t*)carve(512 * 512 * 2);
  bf16_t* W1T   = (bf16_t*)carve(512 * 2048 * 2);
  bf16_t* W2T   = (bf16_t*)carve(512 * 2048 * 2);
  bf16_t* g_bf  = (bf16_t*)carve((size_t)M * 2048 * 2);  // 32 MB
  float*  proj  = (float*)carve((size_t)M * 512 * 4);    // reused as ffn2 out
  float*  h_f   = (float*)carve((size_t)M * 512 * 4);
  float*  f2    = proj;  // proj dead after LN1; FFN2 output aliases it

  // prep: converts + transposes
  k_cvt_bf16<<<4096, 256, 0, stream>>>(x, x_bf, M * 512 / 4);
  k_transpose_bf16<<<dim3(8, 8), 256, 0, stream>>>(Wq, WqT, 512, 512);
  k_transpose_bf16<<<dim3(8, 8), 256, 0, stream>>>(Wk, WkT, 512, 512);
  k_transpose_bf16<<<dim3(8, 8), 256, 0, stream>>>(Wv, WvT, 512, 512);
  k_transpose_bf16<<<dim3(8, 8), 256, 0, stream>>>(Wo, WoT, 512, 512);
  k_transpose_bf16<<<dim3(8, 32), 256, 0, stream>>>(W1, W1T, 512, 2048);
  k_transpose_bf16<<<dim3(32, 8), 256, 0, stream>>>(W2, W2T, 2048, 512);

  // QKV projections (scatter epilogues)
  k_gemm_bt<2><<<dim3(64, 4), 256, 0, stream>>>(x_bf, WqT, nullptr, q_bf, M, 512, 512, nullptr);
  k_gemm_bt<2><<<dim3(64, 4), 256, 0, stream>>>(x_bf, WkT, nullptr, k_bf, M, 512, 512, nullptr);
  k_gemm_bt<3><<<dim3(64, 4), 256, 0, stream>>>(x_bf, WvT, nullptr, vT_bf, M, 512, 512, nullptr);

  // attention (two-pass, poly softmax)
  k_attn<<<1024, 256, 0, stream>>>(q_bf, k_bf, vT_bf, o_bf, exp_c);

  // output projection
  k_gemm_bt<0><<<dim3(64, 4), 256, 0, stream>>>(o_bf, WoT, proj, nullptr, M, 512, 512, nullptr);

  // LN1: h = LN(x + proj); fp32 + bf16
  k_ln<<<2048, 256, 0, stream>>>(x, proj, g1, b1, h_f, h_bf);

  // FFN1: gelu(h @ W1) -> bf16
  k_gemm_bt<4><<<dim3(64, 16), 256, 0, stream>>>(h_bf, W1T, nullptr, g_bf, M, 2048, 512, gelu_c);

  // FFN2: g @ W2 -> fp32
  k_gemm_bt<0><<<dim3(64, 4), 256, 0, stream>>>(g_bf, W2T, f2, nullptr, M, 512, 2048, nullptr);

  // LN2: out = LN(h + ffn)
  k_ln<<<2048, 256, 0, stream>>>(h_f, f2, g2, b2, (float*)d_out, nullptr);
}